// Round 1
// baseline (214.850 us; speedup 1.0000x reference)
//
#include <hip/hip_runtime.h>

#define S_LEN 1024
#define EMB   1024
#define NH    16
#define HD    64
#define BATCH 4
#define M_TOT 4096                 // BATCH * S_LEN
#define QSZ   (BATCH * NH * S_LEN * HD)   // 4194304 elems per Q/K/V tensor

typedef __attribute__((ext_vector_type(4))) float  f32x4;
typedef __attribute__((ext_vector_type(8))) __bf16 bf16x8;

__device__ __forceinline__ unsigned short f2bf(float f) {
  union { float f; unsigned u; } a; a.f = f;
  unsigned r = a.u + 0x7fffu + ((a.u >> 16) & 1u);   // RNE
  return (unsigned short)(r >> 16);
}

// ---------------- fp32 -> bf16 elementwise (vectorized) ----------------
__global__ void cvt_bf16(const float4* __restrict__ in, ushort4* __restrict__ out, int n4) {
  int i = blockIdx.x * blockDim.x + threadIdx.x;
  if (i >= n4) return;
  float4 v = in[i];
  ushort4 o;
  o.x = f2bf(v.x); o.y = f2bf(v.y); o.z = f2bf(v.z); o.w = f2bf(v.w);
  out[i] = o;
}

// ------------- fp32 (K,N) -> bf16 (N,K) transpose via LDS tile ---------
__global__ void cvt_transpose(const float* __restrict__ in, unsigned short* __restrict__ out,
                              int K, int N) {
  __shared__ unsigned short tile[32][33];
  int n0 = blockIdx.x * 32, k0 = blockIdx.y * 32;
  int tx = threadIdx.x, ty = threadIdx.y;   // block (32,8)
  #pragma unroll
  for (int r = ty; r < 32; r += 8)
    tile[r][tx] = f2bf(in[(size_t)(k0 + r) * N + n0 + tx]);
  __syncthreads();
  #pragma unroll
  for (int r = ty; r < 32; r += 8)
    out[(size_t)(n0 + r) * K + k0 + tx] = tile[tx][r];
}

// ---------------- bf16 MFMA GEMM: C = A(M,K) * Bt(N,K)^T + bias --------
// 128x128 tile, 4 waves (2x2 of 64x64), BK=32, global_load_lds width 16.
// EPI 0: scatter to Q/K/V^T bf16 buffers.  EPI 1: fp32 row-major out.
template<int EPI>
__global__ __launch_bounds__(256) void gemm_bt(
    const unsigned short* __restrict__ A,
    const unsigned short* __restrict__ Bt,
    const float* __restrict__ bias,
    void* __restrict__ outp,
    int M, int N, int K)
{
  __shared__ alignas(16) unsigned short As[128 * 32];
  __shared__ alignas(16) unsigned short Bs[128 * 32];
  const int m0 = blockIdx.x * 128, n0 = blockIdx.y * 128;
  const int t = threadIdx.x;
  const int wid = t >> 6, lane = t & 63;
  const int wr = wid >> 1, wc = wid & 1;
  const int lr = lane & 15, lg = lane >> 4;

  f32x4 acc[4][4] = {};

  for (int k0 = 0; k0 < K; k0 += 32) {
    #pragma unroll
    for (int c = 0; c < 2; ++c) {
      int idx8 = (c * 4 + wid) * 64 + lane;       // which 8-elem chunk
      int row  = idx8 >> 2, col = (idx8 & 3) << 3;
      const unsigned short* gA = A  + (size_t)(m0 + row) * K + k0 + col;
      const unsigned short* gB = Bt + (size_t)(n0 + row) * K + k0 + col;
      __builtin_amdgcn_global_load_lds(
          (const __attribute__((address_space(1))) unsigned int*)gA,
          (__attribute__((address_space(3))) unsigned int*)(As + (size_t)(c * 4 + wid) * 512),
          16, 0, 0);
      __builtin_amdgcn_global_load_lds(
          (const __attribute__((address_space(1))) unsigned int*)gB,
          (__attribute__((address_space(3))) unsigned int*)(Bs + (size_t)(c * 4 + wid) * 512),
          16, 0, 0);
    }
    __syncthreads();

    bf16x8 af[4], bfr[4];
    #pragma unroll
    for (int i = 0; i < 4; ++i)
      af[i] = *(const bf16x8*)(As + (wr * 64 + i * 16 + lr) * 32 + lg * 8);
    #pragma unroll
    for (int j = 0; j < 4; ++j)
      bfr[j] = *(const bf16x8*)(Bs + (wc * 64 + j * 16 + lr) * 32 + lg * 8);
    #pragma unroll
    for (int i = 0; i < 4; ++i)
      #pragma unroll
      for (int j = 0; j < 4; ++j)
        acc[i][j] = __builtin_amdgcn_mfma_f32_16x16x32_bf16(af[i], bfr[j], acc[i][j], 0, 0, 0);
    __syncthreads();
  }

  #pragma unroll
  for (int i = 0; i < 4; ++i) {
    #pragma unroll
    for (int j = 0; j < 4; ++j) {
      const int col = n0 + wc * 64 + j * 16 + lr;
      const float bv = bias[col];
      #pragma unroll
      for (int r = 0; r < 4; ++r) {
        const int row = m0 + wr * 64 + i * 16 + lg * 4 + r;
        float v = acc[i][j][r] + bv;
        if (EPI == 0) {
          unsigned short* O = (unsigned short*)outp;
          int bb = row >> 10, ss = row & 1023;
          int sec = col >> 10, cc = col & 1023;
          int h = cc >> 6, d = cc & 63;
          size_t off;
          if (sec < 2)   // Q, K in (b,h,s,d)
            off = (size_t)sec * QSZ + (((size_t)(bb * NH + h) * S_LEN + ss) * HD + d);
          else           // V^T in (b,h,d,s)
            off = 2ull * QSZ + ((size_t)(bb * NH + h) * HD + d) * S_LEN + ss;
          O[off] = f2bf(v);
        } else {
          ((float*)outp)[(size_t)row * (size_t)N + col] = v;
        }
      }
    }
  }
}

// ---------------- causal flash attention, 4 waves x 16 q-rows ----------
__global__ __launch_bounds__(256) void attn_fwd(
    const unsigned short* __restrict__ Q,    // (bh, s, d)
    const unsigned short* __restrict__ Kt,   // (bh, s, d)
    const unsigned short* __restrict__ Vt,   // (bh, d, s)
    unsigned short* __restrict__ attout)     // (b, s, e) bf16
{
  __shared__ alignas(16) unsigned short P_lds[4][16 * 32];
  const int bh = blockIdx.y;
  const int w = threadIdx.x >> 6, lane = threadIdx.x & 63;
  const int q0 = blockIdx.x * 64 + w * 16;
  const int lr = lane & 15, lg = lane >> 4;
  const unsigned short* Qb = Q  + (size_t)bh * S_LEN * HD;
  const unsigned short* Kh = Kt + (size_t)bh * S_LEN * HD;
  const unsigned short* Vh = Vt + (size_t)bh * HD * S_LEN;

  bf16x8 qf[2];
  #pragma unroll
  for (int kk = 0; kk < 2; ++kk)
    qf[kk] = *(const bf16x8*)(Qb + (size_t)(q0 + lr) * HD + kk * 32 + lg * 8);

  float m[4], l[4];
  f32x4 o[4] = {};
  #pragma unroll
  for (int r = 0; r < 4; ++r) { m[r] = -1e30f; l[r] = 0.f; }

  const int nkt = ((q0 + 15) >> 5) + 1;     // causal: tiles with kt*32 <= max q row
  const float scale = 0.125f;

  for (int kt = 0; kt < nkt; ++kt) {
    f32x4 sacc[2] = {};
    #pragma unroll
    for (int nt = 0; nt < 2; ++nt)
      #pragma unroll
      for (int kk = 0; kk < 2; ++kk) {
        bf16x8 kf = *(const bf16x8*)(Kh + (size_t)(kt * 32 + nt * 16 + lr) * HD + kk * 32 + lg * 8);
        sacc[nt] = __builtin_amdgcn_mfma_f32_16x16x32_bf16(qf[kk], kf, sacc[nt], 0, 0, 0);
      }

    float p[2][4], tmax[4];
    #pragma unroll
    for (int r = 0; r < 4; ++r) {
      const int q = q0 + lg * 4 + r;
      float v0 = sacc[0][r] * scale;
      float v1 = sacc[1][r] * scale;
      if (kt * 32 + lr > q)      v0 = -1e30f;
      if (kt * 32 + 16 + lr > q) v1 = -1e30f;
      p[0][r] = v0; p[1][r] = v1;
      tmax[r] = fmaxf(v0, v1);
    }
    #pragma unroll
    for (int off = 1; off < 16; off <<= 1)
      #pragma unroll
      for (int r = 0; r < 4; ++r)
        tmax[r] = fmaxf(tmax[r], __shfl_xor(tmax[r], off, 64));

    float fs[4], rs[4];
    #pragma unroll
    for (int r = 0; r < 4; ++r) {
      float mn = fmaxf(m[r], tmax[r]);
      fs[r] = __expf(m[r] - mn);
      m[r] = mn;
      p[0][r] = __expf(p[0][r] - mn);
      p[1][r] = __expf(p[1][r] - mn);
      rs[r] = p[0][r] + p[1][r];
    }
    #pragma unroll
    for (int off = 1; off < 16; off <<= 1)
      #pragma unroll
      for (int r = 0; r < 4; ++r)
        rs[r] += __shfl_xor(rs[r], off, 64);

    #pragma unroll
    for (int r = 0; r < 4; ++r) {
      l[r] = l[r] * fs[r] + rs[r];
      #pragma unroll
      for (int dt = 0; dt < 4; ++dt)
        o[dt][r] *= fs[r];
    }

    // P (16q x 32k) -> LDS bf16, then re-read in MFMA A-layout
    #pragma unroll
    for (int nt = 0; nt < 2; ++nt)
      #pragma unroll
      for (int r = 0; r < 4; ++r)
        P_lds[w][(lg * 4 + r) * 32 + nt * 16 + lr] = f2bf(p[nt][r]);
    asm volatile("s_waitcnt lgkmcnt(0)" ::: "memory");
    bf16x8 pa = *(const bf16x8*)(&P_lds[w][lr * 32 + lg * 8]);

    #pragma unroll
    for (int dt = 0; dt < 4; ++dt) {
      bf16x8 vf = *(const bf16x8*)(Vh + (size_t)(dt * 16 + lr) * S_LEN + kt * 32 + lg * 8);
      o[dt] = __builtin_amdgcn_mfma_f32_16x16x32_bf16(pa, vf, o[dt], 0, 0, 0);
    }
  }

  const int bb = bh >> 4, h = bh & 15;
  #pragma unroll
  for (int dt = 0; dt < 4; ++dt)
    #pragma unroll
    for (int r = 0; r < 4; ++r) {
      const int q = q0 + lg * 4 + r;
      float v = o[dt][r] / l[r];
      attout[((size_t)(bb * S_LEN + q)) * EMB + h * HD + dt * 16 + lr] = f2bf(v);
    }
}

extern "C" void kernel_launch(void* const* d_in, const int* in_sizes, int n_in,
                              void* d_out, int out_size, void* d_ws, size_t ws_size,
                              hipStream_t stream) {
  const float* x     = (const float*)d_in[0];
  const float* Wqkv  = (const float*)d_in[1];
  const float* bqkv  = (const float*)d_in[2];
  const float* Wproj = (const float*)d_in[3];
  const float* bproj = (const float*)d_in[4];

  unsigned short* xb     = (unsigned short*)d_ws;                  // 4096*1024
  unsigned short* WqkvT  = xb     + (size_t)M_TOT * EMB;           // 3072*1024
  unsigned short* WprojT = WqkvT  + (size_t)3 * EMB * EMB;         // 1024*1024
  unsigned short* qkv    = WprojT + (size_t)EMB * EMB;             // 3 * QSZ
  unsigned short* att    = qkv    + 3ull * QSZ;                    // 4096*1024

  cvt_bf16<<<dim3((M_TOT * EMB / 4 + 255) / 256), dim3(256), 0, stream>>>(
      (const float4*)x, (ushort4*)xb, M_TOT * EMB / 4);
  cvt_transpose<<<dim3(3 * EMB / 32, EMB / 32), dim3(32, 8), 0, stream>>>(Wqkv, WqkvT, EMB, 3 * EMB);
  cvt_transpose<<<dim3(EMB / 32, EMB / 32), dim3(32, 8), 0, stream>>>(Wproj, WprojT, EMB, EMB);

  gemm_bt<0><<<dim3(M_TOT / 128, 3 * EMB / 128), dim3(256), 0, stream>>>(
      xb, WqkvT, bqkv, (void*)qkv, M_TOT, 3 * EMB, EMB);

  attn_fwd<<<dim3(S_LEN / 64, BATCH * NH), dim3(256), 0, stream>>>(
      qkv, qkv + QSZ, qkv + 2ull * QSZ, att);

  gemm_bt<1><<<dim3(M_TOT / 128, EMB / 128), dim3(256), 0, stream>>>(
      att, WprojT, bproj, d_out, M_TOT, EMB, EMB);
}

// Round 2
// 160.163 us; speedup vs baseline: 1.3414x; 1.3414x over previous
//
#include <hip/hip_runtime.h>

#define S_LEN 1024
#define EMB   1024
#define NH    16
#define HD    64
#define BATCH 4
#define M_TOT 4096                 // BATCH * S_LEN
#define QSZ   (BATCH * NH * S_LEN * HD)   // 4194304 elems per Q/K/V tensor

typedef __attribute__((ext_vector_type(4))) float  f32x4;
typedef __attribute__((ext_vector_type(8))) __bf16 bf16x8;

__device__ __forceinline__ unsigned short f2bf(float f) {
  union { float f; unsigned u; } a; a.f = f;
  unsigned r = a.u + 0x7fffu + ((a.u >> 16) & 1u);   // RNE
  return (unsigned short)(r >> 16);
}

// ---------------- fp32 -> bf16 elementwise (vectorized) ----------------
__global__ void cvt_bf16(const float4* __restrict__ in, ushort4* __restrict__ out, int n4) {
  int i = blockIdx.x * blockDim.x + threadIdx.x;
  if (i >= n4) return;
  float4 v = in[i];
  ushort4 o;
  o.x = f2bf(v.x); o.y = f2bf(v.y); o.z = f2bf(v.z); o.w = f2bf(v.w);
  out[i] = o;
}

// ------------- fp32 (K,N) -> bf16 (N,K) transpose via LDS tile ---------
__global__ void cvt_transpose(const float* __restrict__ in, unsigned short* __restrict__ out,
                              int K, int N) {
  __shared__ unsigned short tile[32][33];
  int n0 = blockIdx.x * 32, k0 = blockIdx.y * 32;
  int tx = threadIdx.x, ty = threadIdx.y;   // block (32,8)
  #pragma unroll
  for (int r = ty; r < 32; r += 8)
    tile[r][tx] = f2bf(in[(size_t)(k0 + r) * N + n0 + tx]);
  __syncthreads();
  #pragma unroll
  for (int r = ty; r < 32; r += 8)
    out[(size_t)(n0 + r) * K + k0 + tx] = tile[tx][r];
}

// ---- bf16 (bh, s, d) -> bf16 (bh, d, s) transpose (V -> V^T) ----------
__global__ void transpose_v(const unsigned short* __restrict__ in,
                            unsigned short* __restrict__ out) {
  __shared__ unsigned short tile[64][65];
  const int bh = blockIdx.y, s0 = blockIdx.x * 64;
  const int tx = threadIdx.x, ty = threadIdx.y;   // block (64,4)
  const unsigned short* src = in + (size_t)bh * S_LEN * HD;
  unsigned short* dst = out + (size_t)bh * HD * S_LEN;
  #pragma unroll
  for (int r = ty; r < 64; r += 4)
    tile[r][tx] = src[(size_t)(s0 + r) * HD + tx];
  __syncthreads();
  #pragma unroll
  for (int r = ty; r < 64; r += 4)
    dst[(size_t)r * S_LEN + s0 + tx] = tile[tx][r];
}

// ---------------- bf16 MFMA GEMM: C = A(M,K) * Bt(N,K)^T + bias --------
// 128x128 tile, 4 waves (2x2 of 64x64), BK=32, global_load_lds width 16.
// EPI 0: scatter to Q/K/V bf16 (b,h,s,d); Q pre-scaled by 1/8.
// EPI 1: fp32 row-major out.
template<int EPI>
__global__ __launch_bounds__(256) void gemm_bt(
    const unsigned short* __restrict__ A,
    const unsigned short* __restrict__ Bt,
    const float* __restrict__ bias,
    void* __restrict__ outp,
    int M, int N, int K)
{
  __shared__ alignas(16) unsigned short As[128 * 32];
  __shared__ alignas(16) unsigned short Bs[128 * 32];
  const int m0 = blockIdx.x * 128, n0 = blockIdx.y * 128;
  const int t = threadIdx.x;
  const int wid = t >> 6, lane = t & 63;
  const int wr = wid >> 1, wc = wid & 1;
  const int lr = lane & 15, lg = lane >> 4;

  f32x4 acc[4][4] = {};

  for (int k0 = 0; k0 < K; k0 += 32) {
    #pragma unroll
    for (int c = 0; c < 2; ++c) {
      int idx8 = (c * 4 + wid) * 64 + lane;       // which 8-elem chunk
      int row  = idx8 >> 2, col = (idx8 & 3) << 3;
      const unsigned short* gA = A  + (size_t)(m0 + row) * K + k0 + col;
      const unsigned short* gB = Bt + (size_t)(n0 + row) * K + k0 + col;
      __builtin_amdgcn_global_load_lds(
          (const __attribute__((address_space(1))) unsigned int*)gA,
          (__attribute__((address_space(3))) unsigned int*)(As + (size_t)(c * 4 + wid) * 512),
          16, 0, 0);
      __builtin_amdgcn_global_load_lds(
          (const __attribute__((address_space(1))) unsigned int*)gB,
          (__attribute__((address_space(3))) unsigned int*)(Bs + (size_t)(c * 4 + wid) * 512),
          16, 0, 0);
    }
    __syncthreads();

    bf16x8 af[4], bfr[4];
    #pragma unroll
    for (int i = 0; i < 4; ++i)
      af[i] = *(const bf16x8*)(As + (wr * 64 + i * 16 + lr) * 32 + lg * 8);
    #pragma unroll
    for (int j = 0; j < 4; ++j)
      bfr[j] = *(const bf16x8*)(Bs + (wc * 64 + j * 16 + lr) * 32 + lg * 8);
    #pragma unroll
    for (int i = 0; i < 4; ++i)
      #pragma unroll
      for (int j = 0; j < 4; ++j)
        acc[i][j] = __builtin_amdgcn_mfma_f32_16x16x32_bf16(af[i], bfr[j], acc[i][j], 0, 0, 0);
    __syncthreads();
  }

  #pragma unroll
  for (int i = 0; i < 4; ++i) {
    #pragma unroll
    for (int j = 0; j < 4; ++j) {
      const int col = n0 + wc * 64 + j * 16 + lr;
      const float bv = bias[col];
      #pragma unroll
      for (int r = 0; r < 4; ++r) {
        const int row = m0 + wr * 64 + i * 16 + lg * 4 + r;
        float v = acc[i][j][r] + bv;
        if (EPI == 0) {
          unsigned short* O = (unsigned short*)outp;
          int bb = row >> 10, ss = row & 1023;
          int sec = col >> 10, cc = col & 1023;
          int h = cc >> 6, d = cc & 63;
          if (sec == 0) v *= 0.125f;           // fold softmax scale into Q
          size_t off = (size_t)sec * QSZ +
                       (((size_t)(bb * NH + h) * S_LEN + ss) * HD + d);
          O[off] = f2bf(v);
        } else {
          ((float*)outp)[(size_t)row * (size_t)N + col] = v;
        }
      }
    }
  }
}

// ---------------- causal flash attention ------------------------------
// 4 waves/block, 16 q-rows/wave, KBLK=64, swapped-operand MFMA:
//   QK^T: mfma(Kfrag, Qfrag) -> P[k][q], q = lane&15 (lane-local softmax)
//   PV  : mfma(Vtfrag, Pfrag) -> O^T[d][q]
// K double-buffered in regs (prefetch kt+1); V issued at iter top.
__device__ __forceinline__ void attn_tile(
    int kt, int nkt, int q0, int lr, int lg,
    const unsigned short* __restrict__ Kh,
    const unsigned short* __restrict__ Vh,
    char* Pw, const bf16x8 (&qf)[2],
    bf16x8 (&cur)[8], bf16x8 (&nxt)[8],
    float& m, float& l, f32x4 (&o)[4])
{
  // V for this tile (used ~end of iter; latency hidden under QK+softmax)
  bf16x8 vf[8];
  #pragma unroll
  for (int dt = 0; dt < 4; ++dt)
    #pragma unroll
    for (int kk = 0; kk < 2; ++kk)
      vf[dt * 2 + kk] = *(const bf16x8*)(Vh + (size_t)(dt * 16 + lr) * S_LEN + kt * 64 + kk * 32 + lg * 8);
  // prefetch next K tile (used next iteration)
  if (kt + 1 < nkt) {
    #pragma unroll
    for (int nt = 0; nt < 4; ++nt)
      #pragma unroll
      for (int kk = 0; kk < 2; ++kk)
        nxt[nt * 2 + kk] = *(const bf16x8*)(Kh + (size_t)((kt + 1) * 64 + nt * 16 + lr) * HD + kk * 32 + lg * 8);
  }

  // QK^T: sacc[nt] rows = k (nt*16 + lg*4 + r), cols = q (lr)
  f32x4 sacc[4] = {};
  __builtin_amdgcn_s_setprio(1);
  #pragma unroll
  for (int nt = 0; nt < 4; ++nt)
    #pragma unroll
    for (int kk = 0; kk < 2; ++kk)
      sacc[nt] = __builtin_amdgcn_mfma_f32_16x16x32_bf16(cur[nt * 2 + kk], qf[kk], sacc[nt], 0, 0, 0);
  __builtin_amdgcn_s_setprio(0);

  const int q = q0 + lr;
  float p[16];
  if (kt * 64 + 63 > q0) {        // wave-uniform: tile crosses the diagonal
    #pragma unroll
    for (int nt = 0; nt < 4; ++nt)
      #pragma unroll
      for (int r = 0; r < 4; ++r) {
        int k = kt * 64 + nt * 16 + lg * 4 + r;
        p[nt * 4 + r] = (k > q) ? -1e30f : sacc[nt][r];
      }
  } else {
    #pragma unroll
    for (int nt = 0; nt < 4; ++nt)
      #pragma unroll
      for (int r = 0; r < 4; ++r)
        p[nt * 4 + r] = sacc[nt][r];
  }

  // in-lane max tree (16 vals) + 2 shfls across the 4 replicated lane-groups
  float red[8];
  #pragma unroll
  for (int i = 0; i < 8; ++i) red[i] = fmaxf(p[i], p[i + 8]);
  #pragma unroll
  for (int i = 0; i < 4; ++i) red[i] = fmaxf(red[i], red[i + 4]);
  float pmax = fmaxf(fmaxf(red[0], red[2]), fmaxf(red[1], red[3]));
  pmax = fmaxf(pmax, __shfl_xor(pmax, 16, 64));
  pmax = fmaxf(pmax, __shfl_xor(pmax, 32, 64));

  float mn = fmaxf(m, pmax);
  float fs = __expf(m - mn);
  m = mn;
  #pragma unroll
  for (int i = 0; i < 16; ++i) p[i] = __expf(p[i] - mn);
  float s8[8];
  #pragma unroll
  for (int i = 0; i < 8; ++i) s8[i] = p[i] + p[i + 8];
  #pragma unroll
  for (int i = 0; i < 4; ++i) s8[i] = s8[i] + s8[i + 4];
  float rs = (s8[0] + s8[2]) + (s8[1] + s8[3]);
  rs += __shfl_xor(rs, 16, 64);
  rs += __shfl_xor(rs, 32, 64);
  l = l * fs + rs;
  #pragma unroll
  for (int dt = 0; dt < 4; ++dt)
    #pragma unroll
    for (int r = 0; r < 4; ++r) o[dt][r] *= fs;

  // P -> LDS (row = q = lr, XOR-swizzled), packed 4 consecutive k per b64
  #pragma unroll
  for (int nt = 0; nt < 4; ++nt) {
    ushort4 pk;
    pk.x = f2bf(p[nt * 4 + 0]); pk.y = f2bf(p[nt * 4 + 1]);
    pk.z = f2bf(p[nt * 4 + 2]); pk.w = f2bf(p[nt * 4 + 3]);
    int byt = (lr * 128 + (nt * 16 + lg * 4) * 2) ^ ((lr & 7) << 4);
    *(ushort4*)(Pw + byt) = pk;
  }
  asm volatile("s_waitcnt lgkmcnt(0)" ::: "memory");
  bf16x8 pf[2];
  #pragma unroll
  for (int kk = 0; kk < 2; ++kk) {
    int byt = (lr * 128 + (kk * 32 + lg * 8) * 2) ^ ((lr & 7) << 4);
    pf[kk] = *(const bf16x8*)(Pw + byt);
  }

  // PV: o[dt] rows = d (dt*16 + lg*4 + r), cols = q (lr)
  __builtin_amdgcn_s_setprio(1);
  #pragma unroll
  for (int dt = 0; dt < 4; ++dt)
    #pragma unroll
    for (int kk = 0; kk < 2; ++kk)
      o[dt] = __builtin_amdgcn_mfma_f32_16x16x32_bf16(vf[dt * 2 + kk], pf[kk], o[dt], 0, 0, 0);
  __builtin_amdgcn_s_setprio(0);
}

__global__ __launch_bounds__(256) void attn_fwd(
    const unsigned short* __restrict__ Q,    // (bh, s, d), pre-scaled 1/8
    const unsigned short* __restrict__ K,    // (bh, s, d)
    const unsigned short* __restrict__ Vt,   // (bh, d, s)
    unsigned short* __restrict__ attout)     // (b, s, e) bf16
{
  __shared__ alignas(16) unsigned short P_lds[4][16 * 64];
  const int bx = blockIdx.x;
  const int qt = 15 - (bx >> 6);             // heavy tiles dispatched first
  const int bh = bx & 63;
  const int w = threadIdx.x >> 6, lane = threadIdx.x & 63;
  const int q0 = qt * 64 + w * 16;
  const int lr = lane & 15, lg = lane >> 4;
  char* Pw = (char*)&P_lds[w][0];
  const unsigned short* Qb = Q  + (size_t)bh * (S_LEN * HD);
  const unsigned short* Kh = K  + (size_t)bh * (S_LEN * HD);
  const unsigned short* Vh = Vt + (size_t)bh * (HD * S_LEN);

  bf16x8 qf[2];
  #pragma unroll
  for (int kk = 0; kk < 2; ++kk)
    qf[kk] = *(const bf16x8*)(Qb + (size_t)(q0 + lr) * HD + kk * 32 + lg * 8);

  float m = -1e30f, l = 0.f;
  f32x4 o[4] = {};
  const int nkt = qt + 1;                    // k-tiles of 64

  bf16x8 kfA[8], kfB[8];
  #pragma unroll
  for (int nt = 0; nt < 4; ++nt)
    #pragma unroll
    for (int kk = 0; kk < 2; ++kk)
      kfA[nt * 2 + kk] = *(const bf16x8*)(Kh + (size_t)(nt * 16 + lr) * HD + kk * 32 + lg * 8);

  int kt = 0;
  while (kt + 2 <= nkt) {
    attn_tile(kt,     nkt, q0, lr, lg, Kh, Vh, Pw, qf, kfA, kfB, m, l, o);
    attn_tile(kt + 1, nkt, q0, lr, lg, Kh, Vh, Pw, qf, kfB, kfA, m, l, o);
    kt += 2;
  }
  if (kt < nkt)
    attn_tile(kt, nkt, q0, lr, lg, Kh, Vh, Pw, qf, kfA, kfB, m, l, o);

  // epilogue: O^T[d][q] regs -> LDS -> coalesced (q, d) global stores
  float rl = 1.0f / l;
  #pragma unroll
  for (int dt = 0; dt < 4; ++dt) {
    ushort4 ov;
    ov.x = f2bf(o[dt][0] * rl); ov.y = f2bf(o[dt][1] * rl);
    ov.z = f2bf(o[dt][2] * rl); ov.w = f2bf(o[dt][3] * rl);
    int byt = (lr * 128 + (dt * 16 + lg * 4) * 2) ^ ((lr & 7) << 4);
    *(ushort4*)(Pw + byt) = ov;
  }
  asm volatile("s_waitcnt lgkmcnt(0)" ::: "memory");
  const int bb = bh >> 4, h = bh & 15;
  const int ql = lane >> 2, c = lane & 3;
  #pragma unroll
  for (int s = 0; s < 2; ++s) {
    int byt = (ql * 128 + (c * 16 + s * 8) * 2) ^ ((ql & 7) << 4);
    bf16x8 vrow = *(const bf16x8*)(Pw + byt);
    *(bf16x8*)(attout + (size_t)(bb * S_LEN + q0 + ql) * EMB + h * HD + c * 16 + s * 8) = vrow;
  }
}

extern "C" void kernel_launch(void* const* d_in, const int* in_sizes, int n_in,
                              void* d_out, int out_size, void* d_ws, size_t ws_size,
                              hipStream_t stream) {
  const float* x     = (const float*)d_in[0];
  const float* Wqkv  = (const float*)d_in[1];
  const float* bqkv  = (const float*)d_in[2];
  const float* Wproj = (const float*)d_in[3];
  const float* bproj = (const float*)d_in[4];

  unsigned short* xb     = (unsigned short*)d_ws;                  // 4096*1024 (x bf16, later V^T)
  unsigned short* WqkvT  = xb     + (size_t)M_TOT * EMB;           // 3072*1024
  unsigned short* WprojT = WqkvT  + (size_t)3 * EMB * EMB;         // 1024*1024
  unsigned short* qkv    = WprojT + (size_t)EMB * EMB;             // 3 * QSZ
  unsigned short* att    = qkv    + 3ull * QSZ;                    // 4096*1024

  cvt_bf16<<<dim3((M_TOT * EMB / 4 + 255) / 256), dim3(256), 0, stream>>>(
      (const float4*)x, (ushort4*)xb, M_TOT * EMB / 4);
  cvt_transpose<<<dim3(3 * EMB / 32, EMB / 32), dim3(32, 8), 0, stream>>>(Wqkv, WqkvT, EMB, 3 * EMB);
  cvt_transpose<<<dim3(EMB / 32, EMB / 32), dim3(32, 8), 0, stream>>>(Wproj, WprojT, EMB, EMB);

  gemm_bt<0><<<dim3(M_TOT / 128, 3 * EMB / 128), dim3(256), 0, stream>>>(
      xb, WqkvT, bqkv, (void*)qkv, M_TOT, 3 * EMB, EMB);

  // V (b,h,s,d) -> V^T (b,h,d,s) into xb (dead after gemm1)
  transpose_v<<<dim3(S_LEN / 64, BATCH * NH), dim3(64, 4), 0, stream>>>(
      qkv + 2ull * QSZ, xb);

  attn_fwd<<<dim3(16 * BATCH * NH), dim3(256), 0, stream>>>(
      qkv, qkv + QSZ, xb, att);

  gemm_bt<1><<<dim3(M_TOT / 128, EMB / 128), dim3(256), 0, stream>>>(
      att, WprojT, bproj, d_out, M_TOT, EMB, EMB);
}

// Round 4
// 153.185 us; speedup vs baseline: 1.4025x; 1.0455x over previous
//
#include <hip/hip_runtime.h>

#define S_LEN 1024
#define EMB   1024
#define NH    16
#define HD    64
#define BATCH 4
#define M_TOT 4096                 // BATCH * S_LEN
#define QSZ   (BATCH * NH * S_LEN * HD)   // 4194304 elems per Q/K/V tensor

typedef __attribute__((ext_vector_type(4))) float  f32x4;
typedef __attribute__((ext_vector_type(8))) __bf16 bf16x8;

__device__ __forceinline__ unsigned short f2bf(float f) {
  union { float f; unsigned u; } a; a.f = f;
  unsigned r = a.u + 0x7fffu + ((a.u >> 16) & 1u);   // RNE
  return (unsigned short)(r >> 16);
}

__device__ __forceinline__ float fexp2(float x) {
#if __has_builtin(__builtin_amdgcn_exp2f)
  return __builtin_amdgcn_exp2f(x);
#else
  return exp2f(x);
#endif
}

// ---------------- fp32 -> bf16 elementwise (vectorized) ----------------
__global__ void cvt_bf16(const float4* __restrict__ in, ushort4* __restrict__ out, int n4) {
  int i = blockIdx.x * blockDim.x + threadIdx.x;
  if (i >= n4) return;
  float4 v = in[i];
  ushort4 o;
  o.x = f2bf(v.x); o.y = f2bf(v.y); o.z = f2bf(v.z); o.w = f2bf(v.w);
  out[i] = o;
}

// ------------- fp32 (K,N) -> bf16 (N,K) transpose via LDS tile ---------
__global__ void cvt_transpose(const float* __restrict__ in, unsigned short* __restrict__ out,
                              int K, int N) {
  __shared__ unsigned short tile[32][33];
  int n0 = blockIdx.x * 32, k0 = blockIdx.y * 32;
  int tx = threadIdx.x, ty = threadIdx.y;   // block (32,8)
  #pragma unroll
  for (int r = ty; r < 32; r += 8)
    tile[r][tx] = f2bf(in[(size_t)(k0 + r) * N + n0 + tx]);
  __syncthreads();
  #pragma unroll
  for (int r = ty; r < 32; r += 8)
    out[(size_t)(n0 + r) * K + k0 + tx] = tile[tx][r];
}

// ---- bf16 (bh, s, d) -> bf16 (bh, d, s) transpose (V -> V^T) ----------
__global__ void transpose_v(const unsigned short* __restrict__ in,
                            unsigned short* __restrict__ out) {
  __shared__ unsigned short tile[64][65];
  const int bh = blockIdx.y, s0 = blockIdx.x * 64;
  const int tx = threadIdx.x, ty = threadIdx.y;   // block (64,4)
  const unsigned short* src = in + (size_t)bh * S_LEN * HD;
  unsigned short* dst = out + (size_t)bh * HD * S_LEN;
  #pragma unroll
  for (int r = ty; r < 64; r += 4)
    tile[r][tx] = src[(size_t)(s0 + r) * HD + tx];
  __syncthreads();
  #pragma unroll
  for (int r = ty; r < 64; r += 4)
    dst[(size_t)r * S_LEN + s0 + tx] = tile[tx][r];
}

// ---------------- bf16 MFMA GEMM: C = A(M,K) * Bt(N,K)^T + bias --------
// 128x128 tile, 4 waves (2x2 of 64x64), BK=32, global_load_lds width 16.
// EPI 0: scatter to Q/K/V bf16 (b,h,s,d); Q pre-scaled by 0.125*log2(e).
// EPI 1: fp32 row-major out.
template<int EPI>
__global__ __launch_bounds__(256) void gemm_bt(
    const unsigned short* __restrict__ A,
    const unsigned short* __restrict__ Bt,
    const float* __restrict__ bias,
    void* __restrict__ outp,
    int M, int N, int K)
{
  __shared__ alignas(16) unsigned short As[128 * 32];
  __shared__ alignas(16) unsigned short Bs[128 * 32];
  const int m0 = blockIdx.x * 128, n0 = blockIdx.y * 128;
  const int t = threadIdx.x;
  const int wid = t >> 6, lane = t & 63;
  const int wr = wid >> 1, wc = wid & 1;
  const int lr = lane & 15, lg = lane >> 4;

  f32x4 acc[4][4] = {};

  for (int k0 = 0; k0 < K; k0 += 32) {
    #pragma unroll
    for (int c = 0; c < 2; ++c) {
      int idx8 = (c * 4 + wid) * 64 + lane;       // which 8-elem chunk
      int row  = idx8 >> 2, col = (idx8 & 3) << 3;
      const unsigned short* gA = A  + (size_t)(m0 + row) * K + k0 + col;
      const unsigned short* gB = Bt + (size_t)(n0 + row) * K + k0 + col;
      __builtin_amdgcn_global_load_lds(
          (const __attribute__((address_space(1))) unsigned int*)gA,
          (__attribute__((address_space(3))) unsigned int*)(As + (size_t)(c * 4 + wid) * 512),
          16, 0, 0);
      __builtin_amdgcn_global_load_lds(
          (const __attribute__((address_space(1))) unsigned int*)gB,
          (__attribute__((address_space(3))) unsigned int*)(Bs + (size_t)(c * 4 + wid) * 512),
          16, 0, 0);
    }
    __syncthreads();

    bf16x8 af[4], bfr[4];
    #pragma unroll
    for (int i = 0; i < 4; ++i)
      af[i] = *(const bf16x8*)(As + (wr * 64 + i * 16 + lr) * 32 + lg * 8);
    #pragma unroll
    for (int j = 0; j < 4; ++j)
      bfr[j] = *(const bf16x8*)(Bs + (wc * 64 + j * 16 + lr) * 32 + lg * 8);
    #pragma unroll
    for (int i = 0; i < 4; ++i)
      #pragma unroll
      for (int j = 0; j < 4; ++j)
        acc[i][j] = __builtin_amdgcn_mfma_f32_16x16x32_bf16(af[i], bfr[j], acc[i][j], 0, 0, 0);
    __syncthreads();
  }

  #pragma unroll
  for (int i = 0; i < 4; ++i) {
    #pragma unroll
    for (int j = 0; j < 4; ++j) {
      const int col = n0 + wc * 64 + j * 16 + lr;
      const float bv = bias[col];
      #pragma unroll
      for (int r = 0; r < 4; ++r) {
        const int row = m0 + wr * 64 + i * 16 + lg * 4 + r;
        float v = acc[i][j][r] + bv;
        if (EPI == 0) {
          unsigned short* O = (unsigned short*)outp;
          int bb = row >> 10, ss = row & 1023;
          int sec = col >> 10, cc = col & 1023;
          int h = cc >> 6, d = cc & 63;
          if (sec == 0) v *= 0.18033688f;      // 0.125 * log2(e): exp2-domain scores
          size_t off = (size_t)sec * QSZ +
                       (((size_t)(bb * NH + h) * S_LEN + ss) * HD + d);
          O[off] = f2bf(v);
        } else {
          ((float*)outp)[(size_t)row * (size_t)N + col] = v;
        }
      }
    }
  }
}

// ---------------- causal flash attention ------------------------------
// 512 blocks x 4 waves. Each wave handles the q-group PAIR (63-pi, pi):
// uniform 17 k-tile iterations -> no causal tail. 16 q-rows per group,
// KBLK=64, swapped-operand MFMA (P[k][q], q lane-local softmax), exp2
// domain, defer-max. P redistributed to the PV B-frag layout via 8
// bijective ds_permute pushes (+ static cndmask selects): no LDS, no
// barrier, no bank conflicts.
__device__ __forceinline__ void attn_tile(
    int kt, int nkt, int q0, int lr, int lg,
    const unsigned short* __restrict__ Kh,
    const unsigned short* __restrict__ Vh,
    const bf16x8 (&qf)[2],
    bf16x8 (&cur)[8], bf16x8 (&nxt)[8],
    float& m, float& lp, f32x4 (&o)[4])
{
  // V for this tile (consumed at iter end; latency hidden under QK+softmax)
  bf16x8 vf[8];
  #pragma unroll
  for (int dt = 0; dt < 4; ++dt)
    #pragma unroll
    for (int kk = 0; kk < 2; ++kk)
      vf[dt * 2 + kk] = *(const bf16x8*)(Vh + (size_t)(dt * 16 + lr) * S_LEN + kt * 64 + kk * 32 + lg * 8);
  // prefetch next K tile
  if (kt + 1 < nkt) {
    #pragma unroll
    for (int nt = 0; nt < 4; ++nt)
      #pragma unroll
      for (int kk = 0; kk < 2; ++kk)
        nxt[nt * 2 + kk] = *(const bf16x8*)(Kh + (size_t)((kt + 1) * 64 + nt * 16 + lr) * HD + kk * 32 + lg * 8);
  }

  // QK^T: sacc[nt] rows = k (nt*16 + lg*4 + r), cols = q (lr)
  f32x4 sacc[4] = {};
  __builtin_amdgcn_s_setprio(1);
  #pragma unroll
  for (int nt = 0; nt < 4; ++nt)
    #pragma unroll
    for (int kk = 0; kk < 2; ++kk)
      sacc[nt] = __builtin_amdgcn_mfma_f32_16x16x32_bf16(cur[nt * 2 + kk], qf[kk], sacc[nt], 0, 0, 0);
  __builtin_amdgcn_s_setprio(0);

  float p[16];
  if (kt == nkt - 1) {               // only the diagonal tile needs masking
    const int q = q0 + lr;
    #pragma unroll
    for (int nt = 0; nt < 4; ++nt)
      #pragma unroll
      for (int r = 0; r < 4; ++r) {
        int k = kt * 64 + nt * 16 + lg * 4 + r;
        p[nt * 4 + r] = (k > q) ? -1e30f : sacc[nt][r];
      }
  } else {
    #pragma unroll
    for (int nt = 0; nt < 4; ++nt)
      #pragma unroll
      for (int r = 0; r < 4; ++r)
        p[nt * 4 + r] = sacc[nt][r];
  }

  // per-lane partial max; full reduce + rescale only when needed (defer-max)
  float r8[8], r4[4];
  #pragma unroll
  for (int i = 0; i < 8; ++i) r8[i] = fmaxf(p[i], p[i + 8]);
  #pragma unroll
  for (int i = 0; i < 4; ++i) r4[i] = fmaxf(r8[i], r8[i + 4]);
  float pm = fmaxf(fmaxf(r4[0], r4[1]), fmaxf(r4[2], r4[3]));
  if (__any(pm > m + 11.5f)) {       // 11.5 log2-units ~ 8 nats
    float px = fmaxf(pm, __shfl_xor(pm, 16, 64));
    px = fmaxf(px, __shfl_xor(px, 32, 64));
    float mn = fmaxf(m, px);
    float fs = fexp2(m - mn);
    lp *= fs;
    #pragma unroll
    for (int dt = 0; dt < 4; ++dt)
      #pragma unroll
      for (int r = 0; r < 4; ++r) o[dt][r] *= fs;
    m = mn;
  }
  #pragma unroll
  for (int i = 0; i < 16; ++i) p[i] = fexp2(p[i] - m);

  // per-lane partial sum (cross-lane reduce deferred to epilogue)
  float s8[8], s4[4];
  #pragma unroll
  for (int i = 0; i < 8; ++i) s8[i] = p[i] + p[i + 8];
  #pragma unroll
  for (int i = 0; i < 4; ++i) s4[i] = s8[i] + s8[i + 4];
  lp += (s4[0] + s4[1]) + (s4[2] + s4[3]);

  // pack to bf16 pairs: W.u[i] holds {P[k0][q], P[k0+1][q]},
  // k0 = (i>>1)*16 + lg*4 + 2*(i&1)  (i.e. nt = i>>1, r-pair = 2*(i&1))
  union { unsigned u[8]; __bf16 b[16]; } W;
  #pragma unroll
  for (int i = 0; i < 16; ++i) W.b[i] = (__bf16)p[i];

  // Redistribute P to PV B-frag layout via bijective ds_permute pushes.
  // Target lane (lr,lg) reg T{kk}.u[m4] needs k0 = 32kk + 8lg + 2m4.
  // Instruction (kk,c,phase): source lane (lr,lgs) selects ntl=(lgs&1)^phase,
  // pushes W.u[4kk+2*ntl+c] to lane (2*ntl + (lgs>>1))*16 + lr.
  // Dest stores phase result into m4 = 2*((lg>>1)^phase) + c.
  const int dl0 = ((2 * (lg & 1) + (lg >> 1)) * 16 + lr) << 2;        // phase 0
  const int dl1 = ((2 * ((lg & 1) ^ 1) + (lg >> 1)) * 16 + lr) << 2;  // phase 1
  const bool oddlg = (lg & 1) != 0;
  const bool hb    = (lg >> 1) != 0;
  union { unsigned u[4]; bf16x8 v; } T0, T1;
  #pragma unroll
  for (int kk = 0; kk < 2; ++kk) {
    #pragma unroll
    for (int c = 0; c < 2; ++c) {
      unsigned vlo = W.u[4 * kk + c];        // ntl = 0
      unsigned vhi = W.u[4 * kk + 2 + c];    // ntl = 1
      unsigned s0 = oddlg ? vhi : vlo;       // phase 0: ntl = lg&1
      unsigned s1 = oddlg ? vlo : vhi;       // phase 1: ntl = (lg&1)^1
      unsigned r0 = (unsigned)__builtin_amdgcn_ds_permute(dl0, (int)s0);
      unsigned r1 = (unsigned)__builtin_amdgcn_ds_permute(dl1, (int)s1);
      unsigned* T = kk ? T1.u : T0.u;
      T[c]     = hb ? r1 : r0;
      T[2 + c] = hb ? r0 : r1;
    }
  }

  // PV: o[dt] rows = d (dt*16 + lg*4 + r), cols = q (lr)
  __builtin_amdgcn_s_setprio(1);
  #pragma unroll
  for (int dt = 0; dt < 4; ++dt) {
    o[dt] = __builtin_amdgcn_mfma_f32_16x16x32_bf16(vf[dt * 2 + 0], T0.v, o[dt], 0, 0, 0);
    o[dt] = __builtin_amdgcn_mfma_f32_16x16x32_bf16(vf[dt * 2 + 1], T1.v, o[dt], 0, 0, 0);
  }
  __builtin_amdgcn_s_setprio(0);
}

__device__ __forceinline__ void flash_pass(
    int g, int lr, int lg,
    const unsigned short* __restrict__ Qb,
    const unsigned short* __restrict__ Kh,
    const unsigned short* __restrict__ Vh,
    char* Ep, unsigned short* __restrict__ attout, int bb, int h)
{
  const int q0 = g * 16;
  bf16x8 qf[2];
  #pragma unroll
  for (int kk = 0; kk < 2; ++kk)
    qf[kk] = *(const bf16x8*)(Qb + (size_t)(q0 + lr) * HD + kk * 32 + lg * 8);

  float m = -1e30f, lp = 0.f;
  f32x4 o[4] = {};
  const int nkt = (g >> 2) + 1;

  bf16x8 kfA[8], kfB[8];
  #pragma unroll
  for (int nt = 0; nt < 4; ++nt)
    #pragma unroll
    for (int kk = 0; kk < 2; ++kk)
      kfA[nt * 2 + kk] = *(const bf16x8*)(Kh + (size_t)(nt * 16 + lr) * HD + kk * 32 + lg * 8);

  int kt = 0;
  while (kt + 2 <= nkt) {
    attn_tile(kt,     nkt, q0, lr, lg, Kh, Vh, qf, kfA, kfB, m, lp, o);
    attn_tile(kt + 1, nkt, q0, lr, lg, Kh, Vh, qf, kfB, kfA, m, lp, o);
    kt += 2;
  }
  if (kt < nkt)
    attn_tile(kt, nkt, q0, lr, lg, Kh, Vh, qf, kfA, kfB, m, lp, o);

  float l2 = lp + __shfl_xor(lp, 16, 64);
  float l4 = l2 + __shfl_xor(l2, 32, 64);
  float rl = 1.0f / l4;

  // O^T[d][q] regs -> LDS (row=q, swizzled) -> coalesced (q, d) stores
  #pragma unroll
  for (int dt = 0; dt < 4; ++dt) {
    union { ushort4 s4; __bf16 b[4]; } ov;
    #pragma unroll
    for (int r = 0; r < 4; ++r) ov.b[r] = (__bf16)(o[dt][r] * rl);
    int byt = (lr * 128 + (dt * 16 + lg * 4) * 2) ^ ((lr & 7) << 4);
    *(ushort4*)(Ep + byt) = ov.s4;
  }
  asm volatile("s_waitcnt lgkmcnt(0)" ::: "memory");
  const int lane = lr + lg * 16;
  const int ql = lane >> 2, c = lane & 3;
  #pragma unroll
  for (int s = 0; s < 2; ++s) {
    int byt = (ql * 128 + (c * 16 + s * 8) * 2) ^ ((ql & 7) << 4);
    bf16x8 vrow = *(const bf16x8*)(Ep + byt);
    *(bf16x8*)(attout + (size_t)(bb * S_LEN + q0 + ql) * EMB + h * HD + c * 16 + s * 8) = vrow;
  }
}

__global__ __launch_bounds__(256, 2) void attn_fwd(
    const unsigned short* __restrict__ Q,    // (bh, s, d), pre-scaled
    const unsigned short* __restrict__ K,    // (bh, s, d)
    const unsigned short* __restrict__ Vt,   // (bh, d, s)
    unsigned short* __restrict__ attout)     // (b, s, e) bf16
{
  __shared__ alignas(16) unsigned short Ep_lds[4][16 * 64];
  const int bh = blockIdx.x >> 3;
  const int w = threadIdx.x >> 6, lane = threadIdx.x & 63;
  const int pi = (blockIdx.x & 7) * 4 + w;   // pair index 0..31
  const int lr = lane & 15, lg = lane >> 4;
  char* Ep = (char*)&Ep_lds[w][0];
  const unsigned short* Qb = Q  + (size_t)bh * (S_LEN * HD);
  const unsigned short* Kh = K  + (size_t)bh * (S_LEN * HD);
  const unsigned short* Vh = Vt + (size_t)bh * (HD * S_LEN);
  const int bb = bh >> 4, h = bh & 15;

  flash_pass(63 - pi, lr, lg, Qb, Kh, Vh, Ep, attout, bb, h);  // heavy
  flash_pass(pi,      lr, lg, Qb, Kh, Vh, Ep, attout, bb, h);  // light
}

extern "C" void kernel_launch(void* const* d_in, const int* in_sizes, int n_in,
                              void* d_out, int out_size, void* d_ws, size_t ws_size,
                              hipStream_t stream) {
  const float* x     = (const float*)d_in[0];
  const float* Wqkv  = (const float*)d_in[1];
  const float* bqkv  = (const float*)d_in[2];
  const float* Wproj = (const float*)d_in[3];
  const float* bproj = (const float*)d_in[4];

  unsigned short* xb     = (unsigned short*)d_ws;                  // 4096*1024 (x bf16, later V^T)
  unsigned short* WqkvT  = xb     + (size_t)M_TOT * EMB;           // 3072*1024
  unsigned short* WprojT = WqkvT  + (size_t)3 * EMB * EMB;         // 1024*1024
  unsigned short* qkv    = WprojT + (size_t)EMB * EMB;             // 3 * QSZ
  unsigned short* att    = qkv    + 3ull * QSZ;                    // 4096*1024

  cvt_bf16<<<dim3((M_TOT * EMB / 4 + 255) / 256), dim3(256), 0, stream>>>(
      (const float4*)x, (ushort4*)xb, M_TOT * EMB / 4);
  cvt_transpose<<<dim3(3 * EMB / 32, EMB / 32), dim3(32, 8), 0, stream>>>(Wqkv, WqkvT, EMB, 3 * EMB);
  cvt_transpose<<<dim3(EMB / 32, EMB / 32), dim3(32, 8), 0, stream>>>(Wproj, WprojT, EMB, EMB);

  gemm_bt<0><<<dim3(M_TOT / 128, 3 * EMB / 128), dim3(256), 0, stream>>>(
      xb, WqkvT, bqkv, (void*)qkv, M_TOT, 3 * EMB, EMB);

  // V (b,h,s,d) -> V^T (b,h,d,s) into xb (dead after gemm1)
  transpose_v<<<dim3(S_LEN / 64, BATCH * NH), dim3(64, 4), 0, stream>>>(
      qkv + 2ull * QSZ, xb);

  attn_fwd<<<dim3(8 * BATCH * NH), dim3(256), 0, stream>>>(
      qkv, qkv + QSZ, xb, att);

  gemm_bt<1><<<dim3(M_TOT / 128, EMB / 128), dim3(256), 0, stream>>>(
      att, WprojT, bproj, d_out, M_TOT, EMB, EMB);
}